// Round 5
// baseline (77.009 us; speedup 1.0000x reference)
//
#include <hip/hip_runtime.h>
#include <hip/hip_bf16.h>

#define NEG_BIG 1e10f

// Fused single kernel. TPW consecutive t-values per wave share one NROWS-row
// x-window. Each wave also (redundantly, cheaply) computes its batch's
// src_len = sum(mask[b,:]) -- 8 float4 loads from L1/L2-hot mask.
// lane&15 -> 4 feature cols (float4); lane>>4 = row-phase group in phase 2.
// D hard-wired to 64.
constexpr int TPW = 8;
constexpr int NROWS = 80;  // 64-window + drift r*(TPW-1) <= 2*7 = 14 <= 16

__global__ void __launch_bounds__(256)
length_transform(const float* __restrict__ x,              // (B,S,64) fp32
                 const float* __restrict__ mask,           // (B,S) fp32
                 const float* __restrict__ lengthscale,    // (1,) fp32
                 const int* __restrict__ tgt_lens,         // (B,) int32
                 float* __restrict__ out_feat,             // (B,T,64) fp32
                 float* __restrict__ out_mask,             // (B,T) fp32
                 int B, int S, int T) {
    // per-wave weight table: [row][tslot 0..7] stored as 2x float4
    __shared__ float4 wlds_all[4][NROWS][2];
    const int wid  = threadIdx.x >> 6;
    const int lane = threadIdx.x & 63;
    const int nt = T / TPW;
    int gw = blockIdx.x * 4 + wid;
    const bool active = (gw < B * nt);
    if (!active) gw = 0;                    // compute in-bounds garbage, skip stores
    const int b  = gw / nt;
    const int t0 = (gw - b * nt) * TPW;

    // --- fused prep: src_len = sum(mask[b,:]) ; r = src_len / tgt_len ---
    float msum = 0.f;
    {
        const float4* m4 = (const float4*)(mask + (size_t)b * S);
        const int n4 = S >> 2;
        for (int i = lane; i < n4; i += 64) {
            float4 v = m4[i];
            msum += v.x + v.y + v.z + v.w;
        }
        for (int i = (n4 << 2) + lane; i < S; i += 64)   // tail if S%4 != 0
            msum += mask[(size_t)b * S + i];
        for (int off = 32; off > 0; off >>= 1)
            msum += __shfl_xor(msum, off, 64);
    }
    const float r = msum / (float)tgt_lens[b];

    const float ls = lengthscale[0];
    const float fac = 1.0f / (2.0f * ls * ls);

    // Per-t 64-wide softmax windows, clamped; union window base u0 (NROWS rows).
    int su[TPW]; float c[TPW];
#pragma unroll
    for (int i = 0; i < TPW; ++i) {
        c[i] = r * (float)(t0 + i);
        int s0 = (int)rintf(c[i]) - 32;
        if (s0 < 0) s0 = 0;
        if (s0 > S - 64) s0 = S - 64;
        su[i] = s0;
    }
    int u0 = su[0];                          // min over i (r >= 0, c increasing)
    if (u0 > S - NROWS) u0 = S - NROWS;
    if (u0 < 0) u0 = 0;
#pragma unroll
    for (int i = 0; i < TPW; ++i) {          // force every window inside [u0, u0+NROWS)
        int hi = u0 + (NROWS - 64);
        su[i] = su[i] > hi ? hi : (su[i] < u0 ? u0 : su[i]);
    }

    // Zero the wave-private weight table (no barrier: same wave writes & reads).
    float4 (*wlds)[2] = wlds_all[wid];
    {
        float4* wf = &wlds[0][0];
#pragma unroll
        for (int i = 0; i < (NROWS * 2 + 63) / 64; ++i) {
            int k = i * 64 + lane;
            if (k < NROWS * 2) wf[k] = make_float4(0.f, 0.f, 0.f, 0.f);
        }
    }

    // Phase 1: weights. Analytic max (closest window point to center), so only
    // the 6-shfl sum reduction per t. logit - mx <= 0 always => no overflow.
#pragma unroll
    for (int i = 0; i < TPW; ++i) {
        int s = su[i] + lane;
        float dsv = (float)s - c[i];
        float mv = mask[(size_t)b * S + s];
        float logit = mv * (-dsv * dsv * fac) - (1.0f - mv) * NEG_BIG;
        int sstar = (int)rintf(c[i]);
        if (sstar < su[i]) sstar = su[i];
        if (sstar > su[i] + 63) sstar = su[i] + 63;
        float dstar = (float)sstar - c[i];
        float mx = -dstar * dstar * fac;
        float w = expf(logit - mx);
        float dn = w;
        for (int off = 32; off > 0; off >>= 1)
            dn += __shfl_xor(dn, off, 64);
        w *= 1.0f / fmaxf(dn, 1e-30f);
        ((float*)&wlds[s - u0][i >> 2])[i & 3] = w;
    }

    // Phase 2: group g handles rows == g (mod 4), cols cidx..cidx+3.
    // LDS weight reads are group-broadcast (same addr across 16 lanes) = free.
    const int g = lane >> 4;
    const int cidx = (lane & 15) << 2;
    const float* xp = x + ((size_t)b * S + (size_t)(u0 + g)) * 64 + cidx;
    float4 a[TPW];
#pragma unroll
    for (int i = 0; i < TPW; ++i) a[i] = make_float4(0.f, 0.f, 0.f, 0.f);
#pragma unroll 5
    for (int j = 0; j < NROWS / 4; ++j) {
        float4 v   = *(const float4*)(xp + (size_t)(4 * j) * 64);
        float4 wlo = wlds[4 * j + g][0];
        float4 whi = wlds[4 * j + g][1];
        a[0].x = fmaf(wlo.x, v.x, a[0].x); a[0].y = fmaf(wlo.x, v.y, a[0].y);
        a[0].z = fmaf(wlo.x, v.z, a[0].z); a[0].w = fmaf(wlo.x, v.w, a[0].w);
        a[1].x = fmaf(wlo.y, v.x, a[1].x); a[1].y = fmaf(wlo.y, v.y, a[1].y);
        a[1].z = fmaf(wlo.y, v.z, a[1].z); a[1].w = fmaf(wlo.y, v.w, a[1].w);
        a[2].x = fmaf(wlo.z, v.x, a[2].x); a[2].y = fmaf(wlo.z, v.y, a[2].y);
        a[2].z = fmaf(wlo.z, v.z, a[2].z); a[2].w = fmaf(wlo.z, v.w, a[2].w);
        a[3].x = fmaf(wlo.w, v.x, a[3].x); a[3].y = fmaf(wlo.w, v.y, a[3].y);
        a[3].z = fmaf(wlo.w, v.z, a[3].z); a[3].w = fmaf(wlo.w, v.w, a[3].w);
        a[4].x = fmaf(whi.x, v.x, a[4].x); a[4].y = fmaf(whi.x, v.y, a[4].y);
        a[4].z = fmaf(whi.x, v.z, a[4].z); a[4].w = fmaf(whi.x, v.w, a[4].w);
        a[5].x = fmaf(whi.y, v.x, a[5].x); a[5].y = fmaf(whi.y, v.y, a[5].y);
        a[5].z = fmaf(whi.y, v.z, a[5].z); a[5].w = fmaf(whi.y, v.w, a[5].w);
        a[6].x = fmaf(whi.z, v.x, a[6].x); a[6].y = fmaf(whi.z, v.y, a[6].y);
        a[6].z = fmaf(whi.z, v.z, a[6].z); a[6].w = fmaf(whi.z, v.w, a[6].w);
        a[7].x = fmaf(whi.w, v.x, a[7].x); a[7].y = fmaf(whi.w, v.y, a[7].y);
        a[7].z = fmaf(whi.w, v.z, a[7].z); a[7].w = fmaf(whi.w, v.w, a[7].w);
    }

    // Butterfly across the 4 row-phase groups: afterwards every lane holds the
    // full window sum for all 8 t-slots.
#pragma unroll
    for (int off = 16; off <= 32; off <<= 1) {
#pragma unroll
        for (int i = 0; i < TPW; ++i) {
            a[i].x += __shfl_xor(a[i].x, off, 64);
            a[i].y += __shfl_xor(a[i].y, off, 64);
            a[i].z += __shfl_xor(a[i].z, off, 64);
            a[i].w += __shfl_xor(a[i].w, off, 64);
        }
    }

    if (active) {
        // Group g stores rows t0+g and t0+4+g: 64 lanes write 8 output rows.
        float4 s_lo = (g == 0) ? a[0] : (g == 1) ? a[1] : (g == 2) ? a[2] : a[3];
        float4 s_hi = (g == 0) ? a[4] : (g == 1) ? a[5] : (g == 2) ? a[6] : a[7];
        float* orow = out_feat + ((size_t)b * T + (size_t)(t0 + g)) * 64 + cidx;
        *(float4*)orow = s_lo;
        *(float4*)(orow + (size_t)4 * 64) = s_hi;
        if (lane < TPW)
            out_mask[(size_t)b * T + t0 + lane] = (t0 + lane < tgt_lens[b]) ? 1.0f : 0.0f;
    }
}

extern "C" void kernel_launch(void* const* d_in, const int* in_sizes, int n_in,
                              void* d_out, int out_size, void* d_ws, size_t ws_size,
                              hipStream_t stream) {
    const float* x        = (const float*)d_in[0]; // src_tok_features (B,S,D) fp32
    const float* mask     = (const float*)d_in[1]; // src_mask (B,S) fp32
    const float* ls       = (const float*)d_in[2]; // lengthscale (1,) fp32
    const int*   tgt_lens = (const int*)d_in[3];   // (B,) int32

    int B = in_sizes[3];                 // 8
    int S = in_sizes[1] / B;             // 2048
    int D = in_sizes[0] / (B * S);       // 64 (kernel assumes 64)
    int T = out_size / (B * (D + 1));    // 2048

    float* out_feat = (float*)d_out;
    float* out_mask = out_feat + (size_t)B * T * D;

    int waves = B * (T / TPW);           // 2048 waves
    int grid = (waves + 3) / 4;          // 4 waves (256 thr) per block
    length_transform<<<grid, 256, 0, stream>>>(x, mask, ls, tgt_lens,
                                               out_feat, out_mask, B, S, T);
}

// Round 6
// 69.020 us; speedup vs baseline: 1.1158x; 1.1158x over previous
//
#include <hip/hip_runtime.h>
#include <hip/hip_bf16.h>

#define NEG_BIG 1e10f

// Single fused kernel. TPW consecutive t-values per wave share one NROWS-row
// x-window. Block-level fused prep: all 4 waves of a block share batch b
// (exact when (T/TPW) % 4 == 0), so 256 threads cooperatively compute
// src_len = sum(mask[b,:]) once and broadcast r via LDS.
// lane&15 -> 4 feature cols (float4); lane>>4 = row-phase group in phase 2.
// D hard-wired to 64.
constexpr int TPW = 4;
constexpr int NROWS = 80;   // 64-window + drift r*(TPW-1) <= 2*3 = 6 <= 16

__global__ void __launch_bounds__(256)
length_transform(const float* __restrict__ x,              // (B,S,64) fp32
                 const float* __restrict__ mask,           // (B,S) fp32
                 const float* __restrict__ lengthscale,    // (1,) fp32
                 const int* __restrict__ tgt_lens,         // (B,) int32
                 float* __restrict__ out_feat,             // (B,T,64) fp32
                 float* __restrict__ out_mask,             // (B,T) fp32
                 int B, int S, int T) {
    __shared__ float4 wlds_all[4][NROWS];   // per-wave weight table [row][t0..t3]
    __shared__ float bsum[4];
    __shared__ float rshared;
    const int wid  = threadIdx.x >> 6;
    const int lane = threadIdx.x & 63;
    const int nt = T / TPW;
    int gw = blockIdx.x * 4 + wid;
    const bool active = (gw < B * nt);
    if (!active) gw = 0;                    // compute in-bounds garbage, skip stores
    const int b  = gw / nt;
    const int t0 = (gw - b * nt) * TPW;

    // --- block-level fused prep: r = sum(mask[b,:]) / tgt_len[b] ---
    const int b0 = (blockIdx.x * 4) / nt;   // wave 0's batch; uniform when 4 | nt
    {
        float ps = 0.f;
        const float4* m4 = (const float4*)(mask + (size_t)b0 * S);
        const int n4 = S >> 2;
        for (int i = threadIdx.x; i < n4; i += 256) {
            float4 v = m4[i];
            ps += v.x + v.y + v.z + v.w;
        }
        for (int i = (n4 << 2) + threadIdx.x; i < S; i += 256)
            ps += mask[(size_t)b0 * S + i];
        for (int off = 32; off > 0; off >>= 1)
            ps += __shfl_xor(ps, off, 64);
        if (lane == 0) bsum[wid] = ps;
        __syncthreads();
        if (threadIdx.x == 0)
            rshared = (bsum[0] + bsum[1] + bsum[2] + bsum[3]) / (float)tgt_lens[b0];
        __syncthreads();
    }
    float r = rshared;
    if (b != b0) {                          // cold fallback (never for 4 | nt)
        float ps = 0.f;
        for (int i = lane; i < S; i += 64)
            ps += mask[(size_t)b * S + i];
        for (int off = 32; off > 0; off >>= 1)
            ps += __shfl_xor(ps, off, 64);
        r = ps / (float)tgt_lens[b];
    }

    const float ls = lengthscale[0];
    const float fac = 1.0f / (2.0f * ls * ls);

    // Per-t 64-wide softmax windows, clamped; union window base u0 (NROWS rows).
    int su[TPW]; float c[TPW];
#pragma unroll
    for (int i = 0; i < TPW; ++i) {
        c[i] = r * (float)(t0 + i);
        int s0 = (int)rintf(c[i]) - 32;
        if (s0 < 0) s0 = 0;
        if (s0 > S - 64) s0 = S - 64;
        su[i] = s0;
    }
    int u0 = su[0];                          // min over i (r >= 0, c increasing)
    if (u0 > S - NROWS) u0 = S - NROWS;
    if (u0 < 0) u0 = 0;
#pragma unroll
    for (int i = 0; i < TPW; ++i) {          // force every window inside [u0, u0+NROWS)
        int hi = u0 + (NROWS - 64);
        su[i] = su[i] > hi ? hi : (su[i] < u0 ? u0 : su[i]);
    }

    // Zero the wave-private weight table (wave-private LDS: no barrier needed).
    float4* wlds = wlds_all[wid];
    for (int i = lane; i < NROWS; i += 64)
        wlds[i] = make_float4(0.f, 0.f, 0.f, 0.f);

    // Phase 1: weights. Analytic max (closest window point to center), so only
    // the 6-shfl sum reduction per t. logit - mx <= 0 always => no overflow.
#pragma unroll
    for (int i = 0; i < TPW; ++i) {
        int s = su[i] + lane;
        float dsv = (float)s - c[i];
        float mv = mask[(size_t)b * S + s];
        float logit = mv * (-dsv * dsv * fac) - (1.0f - mv) * NEG_BIG;
        int sstar = (int)rintf(c[i]);
        if (sstar < su[i]) sstar = su[i];
        if (sstar > su[i] + 63) sstar = su[i] + 63;
        float dstar = (float)sstar - c[i];
        float mx = -dstar * dstar * fac;
        float w = expf(logit - mx);
        float dn = w;
        for (int off = 32; off > 0; off >>= 1)
            dn += __shfl_xor(dn, off, 64);
        w *= 1.0f / fmaxf(dn, 1e-30f);
        ((float*)&wlds[s - u0])[i] = w;
    }

    // Phase 2: group g handles rows == g (mod 4), cols cidx..cidx+3.
    // LDS weight reads are group-broadcast (same addr across 16 lanes) = free.
    const int g = lane >> 4;
    const int cidx = (lane & 15) << 2;
    const float* xp = x + ((size_t)b * S + (size_t)(u0 + g)) * 64 + cidx;
    float4 a0 = {0,0,0,0}, a1 = {0,0,0,0}, a2 = {0,0,0,0}, a3 = {0,0,0,0};
#pragma unroll 5
    for (int j = 0; j < NROWS / 4; ++j) {
        float4 v  = *(const float4*)(xp + (size_t)(4 * j) * 64);
        float4 wv = wlds[4 * j + g];
        a0.x = fmaf(wv.x, v.x, a0.x); a0.y = fmaf(wv.x, v.y, a0.y);
        a0.z = fmaf(wv.x, v.z, a0.z); a0.w = fmaf(wv.x, v.w, a0.w);
        a1.x = fmaf(wv.y, v.x, a1.x); a1.y = fmaf(wv.y, v.y, a1.y);
        a1.z = fmaf(wv.y, v.z, a1.z); a1.w = fmaf(wv.y, v.w, a1.w);
        a2.x = fmaf(wv.z, v.x, a2.x); a2.y = fmaf(wv.z, v.y, a2.y);
        a2.z = fmaf(wv.z, v.z, a2.z); a2.w = fmaf(wv.z, v.w, a2.w);
        a3.x = fmaf(wv.w, v.x, a3.x); a3.y = fmaf(wv.w, v.y, a3.y);
        a3.z = fmaf(wv.w, v.z, a3.z); a3.w = fmaf(wv.w, v.w, a3.w);
    }

    // Butterfly across the 4 row-phase groups (lanes l, l^16, l^32, l^48).
#pragma unroll
    for (int off = 16; off <= 32; off <<= 1) {
        a0.x += __shfl_xor(a0.x, off, 64); a0.y += __shfl_xor(a0.y, off, 64);
        a0.z += __shfl_xor(a0.z, off, 64); a0.w += __shfl_xor(a0.w, off, 64);
        a1.x += __shfl_xor(a1.x, off, 64); a1.y += __shfl_xor(a1.y, off, 64);
        a1.z += __shfl_xor(a1.z, off, 64); a1.w += __shfl_xor(a1.w, off, 64);
        a2.x += __shfl_xor(a2.x, off, 64); a2.y += __shfl_xor(a2.y, off, 64);
        a2.z += __shfl_xor(a2.z, off, 64); a2.w += __shfl_xor(a2.w, off, 64);
        a3.x += __shfl_xor(a3.x, off, 64); a3.y += __shfl_xor(a3.y, off, 64);
        a3.z += __shfl_xor(a3.z, off, 64); a3.w += __shfl_xor(a3.w, off, 64);
    }

    if (active) {
        // Group g stores output t0+g: 64 lanes collectively write 4 output rows.
        float4 myacc = a0;
        if (g == 1) myacc = a1;
        else if (g == 2) myacc = a2;
        else if (g == 3) myacc = a3;
        *(float4*)(out_feat + ((size_t)b * T + (size_t)(t0 + g)) * 64 + cidx) = myacc;
        if (lane < TPW)
            out_mask[(size_t)b * T + t0 + lane] = (t0 + lane < tgt_lens[b]) ? 1.0f : 0.0f;
    }
}

extern "C" void kernel_launch(void* const* d_in, const int* in_sizes, int n_in,
                              void* d_out, int out_size, void* d_ws, size_t ws_size,
                              hipStream_t stream) {
    const float* x        = (const float*)d_in[0]; // src_tok_features (B,S,D) fp32
    const float* mask     = (const float*)d_in[1]; // src_mask (B,S) fp32
    const float* ls       = (const float*)d_in[2]; // lengthscale (1,) fp32
    const int*   tgt_lens = (const int*)d_in[3];   // (B,) int32

    int B = in_sizes[3];                 // 8
    int S = in_sizes[1] / B;             // 2048
    int D = in_sizes[0] / (B * S);       // 64 (kernel assumes 64)
    int T = out_size / (B * (D + 1));    // 2048

    float* out_feat = (float*)d_out;
    float* out_mask = out_feat + (size_t)B * T * D;

    int waves = B * (T / TPW);           // 4096 waves
    int grid = (waves + 3) / 4;          // 4 waves (256 thr) per block
    length_transform<<<grid, 256, 0, stream>>>(x, mask, ls, tgt_lens,
                                               out_feat, out_mask, B, S, T);
}